// Round 21
// baseline (242.479 us; speedup 1.0000x reference)
//
#include <hip/hip_runtime.h>
#include <cstdint>

// Problem constants (from reference)
constexpr int B_   = 4096;
constexpr int T_   = 512;
constexpr int DIN  = 10;
constexpr int H_   = 20;
constexpr int DOUT = 2;

typedef float    v2f __attribute__((ext_vector_type(2)));
typedef float    v4f __attribute__((ext_vector_type(4)));
typedef _Float16 v8h __attribute__((ext_vector_type(8)));
typedef __fp16   fp2t __attribute__((ext_vector_type(2)));

constexpr float SCL = 2.885390082f;   // 2*log2(e), folded into W and b

#define CFENCE() asm volatile("" ::: "memory")

__device__ __forceinline__ float tanh_pre(float s) {
    float e = __builtin_amdgcn_exp2f(s);
    float r = __builtin_amdgcn_rcpf(e + 1.0f);
    return fmaf(-2.0f, r, 1.0f);
}

union B8 { v8h v; fp2t p[4]; };

__device__ __forceinline__ v4f mfma16(v8h a, v8h b, v4f c) {
    return __builtin_amdgcn_mfma_f32_16x16x32_f16(a, b, c, 0, 0, 0);
}

// Fused one-MFMA-depth RNN step (skewed, R13 semantics; layouts verified by R20):
//   y(t) = [h1(t); h2(t-1)] = tanh( W . z(t) + b ),  z(t) = [x(t); y(t-1)]
// z layout (64): 0..9 x | 10..11 pad | 12..31 h1 | 32..51 h2 | 52..63 pad
// 3 M-tiles x 2 K-passes; the K-passes use INDEPENDENT accumulators
// (summed with one v4f add) so the serial chain is ONE mfma + add + tanh
// + in-lane pack -- vs R20's four chained MFMAs (1134 cyc/step).
// Row permutation P makes the D->B repack pure in-lane for every hq:
//   P0 = {20..23, 0..3, 4..7, 12..15}, P1 = {24..27, 28..31, 8..11, 16..19},
//   P2 = {-,-,-,-, 32..35, 36..39, -,-,-,-}
extern "C" __global__ void __launch_bounds__(64, 1)
rnn_mz(const float* __restrict__ x,
       const float* __restrict__ w_ih0, const float* __restrict__ w_hh0,
       const float* __restrict__ b_ih0, const float* __restrict__ b_hh0,
       const float* __restrict__ w_ih1, const float* __restrict__ w_hh1,
       const float* __restrict__ b_ih1, const float* __restrict__ b_hh1,
       const float* __restrict__ fc_w, const float* __restrict__ fc_b,
       float* __restrict__ out)
{
    const int lane = threadIdx.x;
    const int n    = lane & 15;            // sample col / A row
    const int hq   = lane >> 4;            // 0..3
    const int samp = blockIdx.x * 16 + n;  // grid=256 -> always < B_

    __shared__ float ldsF[16][20];

    // ---- row-permutation (arithmetic, no arrays -> no scratch) ----
    auto P = [](int T, int m) -> int {
        if (T == 0) return (m < 4) ? 20 + m : ((m < 12) ? m - 4 : m);
        if (T == 1) return (m < 8) ? 24 + m : ((m < 12) ? m : 4 + m);
        return (m >= 4 && m < 12) ? 28 + m : -1;
    };
    // combined-W element (z-indexed), pre-scaled
    auto Wget = [&](int j, int k) -> _Float16 {
        float v = 0.f;
        if (j >= 0) {
            if (j < H_) {
                if (k < DIN)                 v = w_ih0[j * DIN + k];
                else if (k >= 12 && k < 32)  v = w_hh0[j * H_ + (k - 12)];
            } else {
                const int jj = j - H_;
                if (k >= 12 && k < 32)       v = w_ih1[jj * H_ + (k - 12)];
                else if (k >= 32 && k < 52)  v = w_hh1[jj * H_ + (k - 32)];
            }
        }
        return (_Float16)(SCL * v);
    };

    // ---- A fragments (3 tiles x 2 K-passes) + bias C-init + peel mask ----
    v8h A1[3], A2[3];
    v4f biasC[3];
    v4f kmask[3];                      // 1 for j<20 (h1 rows), 0 for h2/pad
    #pragma unroll
    for (int T = 0; T < 3; ++T) {
        const int jr = P(T, n);        // this lane's A row
        #pragma unroll
        for (int e = 0; e < 8; ++e) {
            A1[T][e] = Wget(jr, 8 * hq + e);
            A2[T][e] = Wget(jr, 32 + 8 * hq + e);
        }
        #pragma unroll
        for (int r = 0; r < 4; ++r) {
            const int j = P(T, 4 * hq + r);
            biasC[T][r] = (j < 0) ? 0.f
                        : (j < H_) ? SCL * (b_ih0[j] + b_hh0[j])
                                   : SCL * (b_ih1[j - H_] + b_hh1[j - H_]);
            kmask[T][r] = (j >= 0 && j < H_) ? 1.f : 0.f;
        }
    }
    const v4f zero4 = {0.f, 0.f, 0.f, 0.f};

    // ---- x loads: hq=0 needs x[0..7], hq=1 needs x[8..9] ----
    const float* xr = x + (size_t)samp * (T_ * DIN);
    int xo0, xo1, xo2, xo3;
    if (hq == 1) { xo0 = 8; xo1 = 0; xo2 = 2; xo3 = 4; }
    else         { xo0 = 0; xo1 = 2; xo2 = 4; xo3 = 6; }
    v2f xraw[4];
    auto load_x = [&](int t) {
        const float* bt = xr + (size_t)t * DIN;
        xraw[0] = *reinterpret_cast<const v2f*>(bt + xo0);
        xraw[1] = *reinterpret_cast<const v2f*>(bt + xo1);
        xraw[2] = *reinterpret_cast<const v2f*>(bt + xo2);
        xraw[3] = *reinterpret_cast<const v2f*>(bt + xo3);
    };

    // ---- pack B fragments from (yv, xraw); mapping verified per-hq ----
    B8 B1z, B2z;
    auto pack = [&](const float (&yv)[3][4]) {
        const fp2t z2 = __builtin_amdgcn_cvt_pkrtz(0.f, 0.f);
        if (hq == 0) {
            B1z.p[0] = __builtin_amdgcn_cvt_pkrtz(xraw[0].x, xraw[0].y);
            B1z.p[1] = __builtin_amdgcn_cvt_pkrtz(xraw[1].x, xraw[1].y);
            B1z.p[2] = __builtin_amdgcn_cvt_pkrtz(xraw[2].x, xraw[2].y);
            B1z.p[3] = __builtin_amdgcn_cvt_pkrtz(xraw[3].x, xraw[3].y);
            B2z.p[0] = __builtin_amdgcn_cvt_pkrtz(yv[0][0], yv[0][1]);
            B2z.p[1] = __builtin_amdgcn_cvt_pkrtz(yv[0][2], yv[0][3]);
            B2z.p[2] = __builtin_amdgcn_cvt_pkrtz(yv[1][0], yv[1][1]);
            B2z.p[3] = __builtin_amdgcn_cvt_pkrtz(yv[1][2], yv[1][3]);
        } else if (hq == 1) {
            B1z.p[0] = __builtin_amdgcn_cvt_pkrtz(xraw[0].x, xraw[0].y);
            B1z.p[1] = z2;
            B1z.p[2] = __builtin_amdgcn_cvt_pkrtz(yv[0][0], yv[0][1]);
            B1z.p[3] = __builtin_amdgcn_cvt_pkrtz(yv[0][2], yv[0][3]);
            B2z.p[0] = __builtin_amdgcn_cvt_pkrtz(yv[1][0], yv[1][1]);
            B2z.p[1] = __builtin_amdgcn_cvt_pkrtz(yv[1][2], yv[1][3]);
            B2z.p[2] = __builtin_amdgcn_cvt_pkrtz(yv[2][0], yv[2][1]);
            B2z.p[3] = __builtin_amdgcn_cvt_pkrtz(yv[2][2], yv[2][3]);
        } else if (hq == 2) {
            B1z.p[0] = __builtin_amdgcn_cvt_pkrtz(yv[0][0], yv[0][1]);
            B1z.p[1] = __builtin_amdgcn_cvt_pkrtz(yv[0][2], yv[0][3]);
            B1z.p[2] = __builtin_amdgcn_cvt_pkrtz(yv[1][0], yv[1][1]);
            B1z.p[3] = __builtin_amdgcn_cvt_pkrtz(yv[1][2], yv[1][3]);
            B2z.p[0] = __builtin_amdgcn_cvt_pkrtz(yv[2][0], yv[2][1]);
            B2z.p[1] = __builtin_amdgcn_cvt_pkrtz(yv[2][2], yv[2][3]);
            B2z.p[2] = z2; B2z.p[3] = z2;
        } else {
            B1z.p[0] = __builtin_amdgcn_cvt_pkrtz(yv[0][0], yv[0][1]);
            B1z.p[1] = __builtin_amdgcn_cvt_pkrtz(yv[0][2], yv[0][3]);
            B1z.p[2] = __builtin_amdgcn_cvt_pkrtz(yv[1][0], yv[1][1]);
            B1z.p[3] = __builtin_amdgcn_cvt_pkrtz(yv[1][2], yv[1][3]);
            B2z.p[0] = z2; B2z.p[1] = z2; B2z.p[2] = z2; B2z.p[3] = z2;
        }
    };

    // ---- initial B: y(-1)=0 with x(0) ----
    load_x(0);
    {
        float yz[3][4] = {};
        pack(yz);
    }
    load_x(1);

    // one fused step: MFMA (1-deep) -> tanh -> pack(yv, x(t+1)) -> prefetch
    float yv[3][4];
    auto step = [&](bool peel, int tnext) {
        v4f D[3];
        #pragma unroll
        for (int T = 0; T < 3; ++T) {
            v4f d1 = mfma16(A1[T], B1z.v, biasC[T]);
            v4f d2 = mfma16(A2[T], B2z.v, zero4);
            D[T] = d1 + d2;
        }
        #pragma unroll
        for (int T = 0; T < 3; ++T)
            #pragma unroll
            for (int r = 0; r < 4; ++r) {
                float u = tanh_pre(D[T][r]);
                yv[T][r] = peel ? u * kmask[T][r] : u;
            }
        pack(yv);
        load_x(tnext);
    };

    // ---- t=0 (peel: h2 half forced to 0), then t=1..511 ----
    step(true, 2);
    for (int t = 1; t < T_; ++t)
        step(false, (t + 2 < T_) ? (t + 2) : (T_ - 1));

    // ---- epilogue: one more MFMA to get y(512) = [h1(512); h2(511)] ----
    float h2v[3][4];
    {
        v4f D[3];
        #pragma unroll
        for (int T = 0; T < 3; ++T) {
            v4f d1 = mfma16(A1[T], B1z.v, biasC[T]);
            v4f d2 = mfma16(A2[T], B2z.v, zero4);
            D[T] = d1 + d2;
        }
        #pragma unroll
        for (int T = 0; T < 3; ++T)
            #pragma unroll
            for (int r = 0; r < 4; ++r)
                h2v[T][r] = tanh_pre(D[T][r]);
    }
    // publish j>=20 values (h2(511)[j-20]) to LDS
    CFENCE();
    #pragma unroll
    for (int T = 0; T < 3; ++T)
        #pragma unroll
        for (int r = 0; r < 4; ++r) {
            const int j = P(T, 4 * hq + r);
            if (j >= H_) ldsF[n][j - H_] = h2v[T][r];
        }
    CFENCE();

    // ---- FC: lanes hq<2 emit out[samp][hq] ----
    if (hq < DOUT) {
        float acc = fc_b[hq];
        #pragma unroll
        for (int j = 0; j < H_; ++j)
            acc = fmaf(ldsF[n][j], fc_w[hq * H_ + j], acc);
        out[samp * DOUT + hq] = acc;
    }
}

extern "C" void kernel_launch(void* const* d_in, const int* in_sizes, int n_in,
                              void* d_out, int out_size, void* d_ws, size_t ws_size,
                              hipStream_t stream) {
    (void)in_sizes; (void)n_in; (void)d_ws; (void)ws_size; (void)out_size;
    const float* x     = (const float*)d_in[0];
    const float* w_ih0 = (const float*)d_in[1];
    const float* w_hh0 = (const float*)d_in[2];
    const float* b_ih0 = (const float*)d_in[3];
    const float* b_hh0 = (const float*)d_in[4];
    const float* w_ih1 = (const float*)d_in[5];
    const float* w_hh1 = (const float*)d_in[6];
    const float* b_ih1 = (const float*)d_in[7];
    const float* b_hh1 = (const float*)d_in[8];
    const float* fc_w  = (const float*)d_in[9];
    const float* fc_b  = (const float*)d_in[10];
    float* out = (float*)d_out;

    hipLaunchKernelGGL(rnn_mz, dim3(B_ / 16), dim3(64), 0, stream,
                       x, w_ih0, w_hh0, b_ih0, b_hh0,
                       w_ih1, w_hh1, b_ih1, b_hh1, fc_w, fc_b, out);
}